// Round 4
// baseline (243.781 us; speedup 1.0000x reference)
//
#include <hip/hip_runtime.h>

typedef unsigned short u16;
typedef unsigned int u32;
typedef __attribute__((ext_vector_type(8))) short short8;   // 8 bf16 = MFMA A/B frag
typedef __attribute__((ext_vector_type(4))) float f32x4;
typedef __attribute__((ext_vector_type(16))) float f32x16;
typedef __attribute__((ext_vector_type(2))) unsigned int u32x2;

__device__ __forceinline__ float bf2f(u16 u){
  union { u32 i; float f; } x; x.i = ((u32)u) << 16; return x.f;
}
__device__ __forceinline__ u16 f2bf(float f){
  union { float f; u32 i; } x; x.f = f;
  u32 r = x.i + 0x7fffu + ((x.i >> 16) & 1u);   // RNE
  return (u16)(r >> 16);
}
__device__ __forceinline__ u32 pack2(float a, float b){
  return (u32)f2bf(a) | ((u32)f2bf(b) << 16);
}
__device__ __forceinline__ u32 cvtpk(float a, float b){
  u32 r; asm("v_cvt_pk_bf16_f32 %0, %1, %2" : "=v"(r) : "v"(a), "v"(b)); return r;
}
__device__ __forceinline__ float bf_lo(u32 w){
  union { u32 i; float f; } x; x.i = w << 16; return x.f;
}
__device__ __forceinline__ float bf_hi(u32 w){
  union { u32 i; float f; } x; x.i = w & 0xffff0000u; return x.f;
}
__device__ __forceinline__ f32x16 mfma32(short8 a, short8 b, f32x16 c){
  return __builtin_amdgcn_mfma_f32_32x32x16_bf16(a, b, c, 0, 0, 0);
}
__device__ __forceinline__ f32x4 mfma16(short8 a, short8 b, f32x4 c){
  return __builtin_amdgcn_mfma_f32_16x16x32_bf16(a, b, c, 0, 0, 0);
}

// ------------------------------------------------------------------
__global__ void cast_kernel(const float* __restrict__ src, u16* __restrict__ dst, int n){
  int i = (blockIdx.x * blockDim.x + threadIdx.x) * 4;
  if (i >= n) return;
  f32x4 v = *(const f32x4*)(src + i);
  *(u32*)(dst + i)     = pack2(v[0], v[1]);
  *(u32*)(dst + i + 2) = pack2(v[2], v[3]);
}

// ------------------------------------------------------------------
// 128x128-tile GEMM, K=768. C[m][n] = sum_k A[m][k]*B[n][k] + bias[n]
// ------------------------------------------------------------------
template<bool AF32, bool QKV>
__global__ __launch_bounds__(256) void gemm_k768(
    const void* __restrict__ Ap, const u16* __restrict__ Bp,
    const float* __restrict__ bias,
    void* __restrict__ o0, u16* __restrict__ ok, u16* __restrict__ ov)
{
  __shared__ u16 As[128][40];
  __shared__ u16 Bs[128][40];
  const int bm0 = blockIdx.x * 128, bn0 = blockIdx.y * 128;
  const int tid = threadIdx.x, lane = tid & 63, wave = tid >> 6;
  const int g = lane >> 4, m16 = lane & 15;
  const int wr = wave >> 1, wc = wave & 1;

  f32x4 acc[4][4];
  #pragma unroll
  for (int i = 0; i < 4; ++i)
    #pragma unroll
    for (int j = 0; j < 4; ++j) acc[i][j] = (f32x4){0.f, 0.f, 0.f, 0.f};

  const int br = tid >> 1, bh8 = (tid & 1) * 16;

  for (int k0 = 0; k0 < 768; k0 += 32) {
    __syncthreads();
    if constexpr (AF32) {
      const float* A = (const float*)Ap;
      #pragma unroll
      for (int p = 0; p < 2; ++p) {
        int slot = tid + p * 256;
        int r = slot >> 2, c8 = (slot & 3) * 8;
        const float* src = A + (size_t)(bm0 + r) * 768 + k0 + c8;
        f32x4 a0 = *(const f32x4*)src;
        f32x4 a1 = *(const f32x4*)(src + 4);
        u32* d = (u32*)&As[r][c8];
        d[0] = pack2(a0[0], a0[1]); d[1] = pack2(a0[2], a0[3]);
        d[2] = pack2(a1[0], a1[1]); d[3] = pack2(a1[2], a1[3]);
      }
    } else {
      const u16* A = (const u16*)Ap;
      const u16* src = A + (size_t)(bm0 + br) * 768 + k0 + bh8;
      *(short8*)&As[br][bh8]     = *(const short8*)src;
      *(short8*)&As[br][bh8 + 8] = *(const short8*)(src + 8);
    }
    const u16* bsrc = Bp + (size_t)(bn0 + br) * 768 + k0 + bh8;
    *(short8*)&Bs[br][bh8]     = *(const short8*)bsrc;
    *(short8*)&Bs[br][bh8 + 8] = *(const short8*)(bsrc + 8);
    __syncthreads();

    short8 af[4], bf[4];
    #pragma unroll
    for (int i = 0; i < 4; ++i) {
      af[i] = *(const short8*)&As[wr * 64 + i * 16 + m16][g * 8];
      bf[i] = *(const short8*)&Bs[wc * 64 + i * 16 + m16][g * 8];
    }
    #pragma unroll
    for (int i = 0; i < 4; ++i)
      #pragma unroll
      for (int j = 0; j < 4; ++j)
        acc[i][j] = __builtin_amdgcn_mfma_f32_16x16x32_bf16(af[i], bf[j], acc[i][j], 0, 0, 0);
  }

  #pragma unroll
  for (int i = 0; i < 4; ++i) {
    #pragma unroll
    for (int j = 0; j < 4; ++j) {
      int n = bn0 + wc * 64 + j * 16 + m16;
      float bs = bias[n];
      #pragma unroll
      for (int r = 0; r < 4; ++r) {
        int m = bm0 + wr * 64 + i * 16 + g * 4 + r;
        float v = acc[i][j][r] + bs;
        if constexpr (QKV) {
          int b = m / 2304, t = m - b * 2304;
          int which = n / 768, rem = n - which * 768;
          int hh = rem >> 6, d = rem & 63;
          u16* dst = which == 0 ? (u16*)o0 : (which == 1 ? ok : ov);
          dst[(size_t)((b * 12 + hh) * 2304 + t) * 64 + d] = f2bf(v);
        } else {
          ((float*)o0)[(size_t)m * 768 + n] = v;
        }
      }
    }
  }
}

// ------------------------------------------------------------------
// v [bh][2304][64] -> vT [bh][64][2304]
// ------------------------------------------------------------------
__global__ __launch_bounds__(256) void vtrans(const u16* __restrict__ v, u16* __restrict__ vT){
  const int bh = blockIdx.y, t0 = blockIdx.x * 64;
  __shared__ u16 Tl[64][66];
  const int tid = threadIdx.x;
  #pragma unroll
  for (int p = 0; p < 2; ++p) {
    int slot = tid + p * 256;
    int r = slot >> 3, c0 = (slot & 7) * 8;
    short8 val = *(const short8*)(v + (size_t)(bh * 2304 + t0 + r) * 64 + c0);
    #pragma unroll
    for (int j = 0; j < 8; ++j) Tl[c0 + j][r] = (u16)val[j];
  }
  __syncthreads();
  #pragma unroll
  for (int p = 0; p < 2; ++p) {
    int slot = tid + p * 256;
    int d = slot >> 3, c0 = (slot & 7) * 8;
    short8 o;
    #pragma unroll
    for (int j = 0; j < 8; ++j) o[j] = (short)Tl[d][c0 + j];
    *(short8*)(vT + ((size_t)bh * 64 + d) * 2304 + t0 + c0) = o;
  }
}

// ------------------------------------------------------------------
// Barrier-free-in-loop fused attention, 32x32x16 MFMA, split-K x2.
// Block = 96 q-rows x one bh; 6 waves: wave w (wq = w%3) handles q-rows
// [32wq,32wq+32), k-tiles [0,18) for w<3 and [18,36) for w>=3.
// Flash merge of the two k-halves via LDS at the end.
// ------------------------------------------------------------------
#define LOG2E 1.4426950408889634f
#define SSC   0.18033688011f      /* 0.125 * LOG2E */

__global__ __launch_bounds__(384, 3) void attn_fused32(
    const u16* __restrict__ qbuf, const u16* __restrict__ kbuf, const u16* __restrict__ vTbuf,
    const u16* __restrict__ rphb, const u16* __restrict__ rpwb, u16* __restrict__ aout)
{
  // XCD-chunked swizzle: 576 = 8 * 72; 72 consecutive blocks per XCD = 3 full bh
  int flat = blockIdx.x;
  flat = (flat & 7) * 72 + (flat >> 3);
  const int bh = flat / 24, qb = flat - bh * 24;
  const int q0 = qb * 96;
  const int qh0 = qb * 2;

  const int tid = threadIdx.x, wave = tid >> 6, lane = tid & 63;
  const int l31 = lane & 31, h = lane >> 5;
  const int m16 = lane & 15, g = lane >> 4;
  const int wq = wave % 3;          // which 32 q-rows
  const int upper = wave >= 3;      // which k-half

  __shared__ u16 RelH[96][52];      // bf16, pre-scaled by LOG2E
  __shared__ u16 RelW[96][52];
  __shared__ float Comb[3][64][35]; // [wq][lane][32 O | m | l], pad 35 -> conflict-free
  __shared__ u16 Olds[3][32][72];   // epilogue transpose buffer (lower waves)

  const size_t bhq = (size_t)bh * 2304;

  // ---- prologue: each wave builds ONE table for its 32 q-rows via MFMA ----
  {
    const u16* rt = upper ? rpwb : rphb;
    u16* tbl = upper ? &RelW[0][0] : &RelH[0][0];
    #pragma unroll
    for (int half = 0; half < 2; ++half) {
      const int it = wq * 2 + half;
      const u16* qap = qbuf + (bhq + q0 + it * 16 + m16) * 64;
      short8 qa0 = *(const short8*)(qap + g * 8);
      short8 qa1 = *(const short8*)(qap + 32 + g * 8);
      for (int jt = 0; jt < 6; ++jt) {
        f32x4 c = {0.f, 0.f, 0.f, 0.f};
        const u16* bp = rt + (jt * 16 + m16) * 64;
        short8 b0 = *(const short8*)(bp + g * 8);
        short8 b1 = *(const short8*)(bp + 32 + g * 8);
        c = mfma16(qa0, b0, c);
        c = mfma16(qa1, b1, c);
        const int j = jt * 16 + m16;
        #pragma unroll
        for (int r = 0; r < 4; ++r) {
          const int ql = it * 16 + g * 4 + r;
          const int base = upper ? (ql >= 48 ? ql - 48 : ql) : (qh0 + (ql >= 48 ? 1 : 0));
          const int kidx = base - j + 47;
          if (kidx >= 0 && kidx < 48) tbl[ql * 52 + kidx] = f2bf(c[r] * LOG2E);
        }
      }
    }
  }
  __syncthreads();

  // ---- persistent Q B-frags ----
  const int qloc = wq * 32 + l31;
  const u16* qrp = qbuf + (bhq + q0 + qloc) * 64;
  short8 qf0 = *(const short8*)(qrp + h * 8);
  short8 qf1 = *(const short8*)(qrp + 16 + h * 8);
  short8 qf2 = *(const short8*)(qrp + 32 + h * 8);
  short8 qf3 = *(const short8*)(qrp + 48 + h * 8);

  f32x16 oA, oB;
  #pragma unroll
  for (int i = 0; i < 16; ++i) { oA[i] = 0.f; oB[i] = 0.f; }
  float mrun = -1e30f;
  float lr0 = 0.f, lr1 = 0.f, lr2 = 0.f, lr3 = 0.f;
  const u16* kbase = kbuf + bhq * 64;
  const u16* vbase = vTbuf + (size_t)bh * 64 * 2304;
  const int kt0 = upper ? 18 : 0;

  for (int kti = 0; kti < 18; ++kti) {
    const int kt = kt0 + kti;
    const int k0 = kt * 64;
    const int kh0 = (kt * 4) / 3;            // k0 / 48
    const int rem0 = k0 - kh0 * 48;          // in {0,16,32}

    // ---- issue ALL global loads for this tile first (K then V) ----
    short8 ka0[4], ka1[4], vva[4], vvb[4];
    #pragma unroll
    for (int dc = 0; dc < 4; ++dc) {
      ka0[dc] = *(const short8*)(kbase + (size_t)(k0 + l31) * 64 + dc * 16 + h * 8);
      ka1[dc] = *(const short8*)(kbase + (size_t)(k0 + 32 + l31) * 64 + dc * 16 + h * 8);
    }
    #pragma unroll
    for (int j = 0; j < 4; ++j) {
      vva[j] = *(const short8*)(vbase + (size_t)l31 * 2304 + k0 + j * 16 + h * 8);
      vvb[j] = *(const short8*)(vbase + (size_t)(32 + l31) * 2304 + k0 + j * 16 + h * 8);
    }

    // bias reads (LDS, independent)
    float rh0 = bf2f(RelH[qloc][kh0]);
    float rh1 = bf2f(RelH[qloc][kh0 + 1]);
    u32x2 rw[8];
    float rhg[8];
    #pragma unroll
    for (int ta = 0; ta < 8; ++ta) {         // group of 4 consecutive k
      const int s0 = rem0 + (ta >> 2) * 32 + (ta & 3) * 8 + h * 4;
      const int kwb = s0 >= 48 ? s0 - 48 : s0;   // multiple of 4 -> b64 aligned
      rhg[ta] = s0 >= 48 ? rh1 : rh0;
      rw[ta] = *(const u32x2*)&RelW[qloc][kwb];
    }

    // ---- QK^T: S^T[64k][32q] ----
    f32x16 st0, st1;
    #pragma unroll
    for (int i = 0; i < 16; ++i) { st0[i] = 0.f; st1[i] = 0.f; }
    #pragma unroll
    for (int dc = 0; dc < 4; ++dc) {
      short8 qfc = dc == 0 ? qf0 : dc == 1 ? qf1 : dc == 2 ? qf2 : qf3;
      st0 = mfma32(ka0[dc], qfc, st0);
      st1 = mfma32(ka1[dc], qfc, st1);
    }

    // ---- logits + per-lane tmax ----
    float tmax = -1e30f;
    #pragma unroll
    for (int t = 0; t < 2; ++t) {
      f32x16& stt = t ? st1 : st0;
      #pragma unroll
      for (int a = 0; a < 4; ++a) {
        const int ta = t * 4 + a;
        const float b0 = rhg[ta] + bf_lo(rw[ta].x);
        const float b1 = rhg[ta] + bf_hi(rw[ta].x);
        const float b2 = rhg[ta] + bf_lo(rw[ta].y);
        const float b3 = rhg[ta] + bf_hi(rw[ta].y);
        stt[a * 4 + 0] = fmaf(stt[a * 4 + 0], SSC, b0);
        stt[a * 4 + 1] = fmaf(stt[a * 4 + 1], SSC, b1);
        stt[a * 4 + 2] = fmaf(stt[a * 4 + 2], SSC, b2);
        stt[a * 4 + 3] = fmaf(stt[a * 4 + 3], SSC, b3);
        tmax = fmaxf(tmax, fmaxf(fmaxf(stt[a * 4 + 0], stt[a * 4 + 1]),
                                 fmaxf(stt[a * 4 + 2], stt[a * 4 + 3])));
      }
    }

    // ---- defer-max online softmax (log2 domain) ----
    if (__any(tmax > mrun + 8.f)) {
      float tm = fmaxf(tmax, __shfl_xor(tmax, 32));
      float mnew = fmaxf(mrun, tm);
      float al = exp2f(mrun - mnew);
      #pragma unroll
      for (int i = 0; i < 16; ++i) { oA[i] *= al; oB[i] *= al; }
      lr0 *= al; lr1 *= al; lr2 *= al; lr3 *= al;
      mrun = mnew;
    }
    #pragma unroll
    for (int i = 0; i < 16; ++i) {
      st0[i] = exp2f(st0[i] - mrun);
      st1[i] = exp2f(st1[i] - mrun);
    }
    #pragma unroll
    for (int i = 0; i < 4; ++i) {
      lr0 += st0[4 * i + 0] + st1[4 * i + 0];
      lr1 += st0[4 * i + 1] + st1[4 * i + 1];
      lr2 += st0[4 * i + 2] + st1[4 * i + 2];
      lr3 += st0[4 * i + 3] + st1[4 * i + 3];
    }

    // ---- pack P -> bf16, lane^32 exchange, PV ----
    #pragma unroll
    for (int j = 0; j < 4; ++j) {
      f32x16& stt = (j >> 1) ? st1 : st0;
      const int a0 = (j & 1) * 2;
      u32 A00 = cvtpk(stt[a0 * 4 + 0], stt[a0 * 4 + 1]);
      u32 A01 = cvtpk(stt[a0 * 4 + 2], stt[a0 * 4 + 3]);
      u32 A10 = cvtpk(stt[a0 * 4 + 4], stt[a0 * 4 + 5]);
      u32 A11 = cvtpk(stt[a0 * 4 + 6], stt[a0 * 4 + 7]);
      u32 sx0 = __shfl_xor(A00, 32), sx1 = __shfl_xor(A01, 32);
      u32 sy0 = __shfl_xor(A10, 32), sy1 = __shfl_xor(A11, 32);
      short8 pb;
      u32* pw = (u32*)&pb;
      pw[0] = h ? sy0 : A00;
      pw[1] = h ? sy1 : A01;
      pw[2] = h ? A10 : sx0;
      pw[3] = h ? A11 : sx1;
      oA = mfma32(vva[j], pb, oA);
      oB = mfma32(vvb[j], pb, oB);
    }
  }

  // ---- split-K merge ----
  float lp = lr0 + lr1 + lr2 + lr3;
  lp += __shfl_xor(lp, 32);                 // per-q partial sum of this k-half
  if (upper) {
    float* c = &Comb[wq][lane][0];
    #pragma unroll
    for (int i = 0; i < 16; ++i) { c[i] = oA[i]; c[16 + i] = oB[i]; }
    c[32] = mrun; c[33] = lp;
  }
  __syncthreads();
  if (upper) return;

  const float* c = &Comb[wq][lane][0];
  float mb = c[32], lb = c[33];
  float m = fmaxf(mrun, mb);
  float fa = exp2f(mrun - m), fb = exp2f(mb - m);
  const float inv = 1.0f / (lp * fa + lb * fb);
  fa *= inv; fb *= inv;

  // ---- epilogue: normalize+merge, transpose via LDS, coalesced store ----
  #pragma unroll
  for (int dt = 0; dt < 2; ++dt) {
    const f32x16& oo = dt ? oB : oA;
    const int coff = dt * 16;
    #pragma unroll
    for (int rp = 0; rp < 8; ++rp) {
      float v0 = oo[2 * rp]     * fa + c[coff + 2 * rp]     * fb;
      float v1 = oo[2 * rp + 1] * fa + c[coff + 2 * rp + 1] * fb;
      u32 w = cvtpk(v0, v1);
      const int d = 32 * dt + 2 * (rp & 1) + 8 * (rp >> 1) + 4 * h;
      *(u32*)&Olds[wq][l31][d] = w;
    }
  }
  asm volatile("s_waitcnt lgkmcnt(0)" ::: "memory");
  const int b = bh / 12, head = bh - b * 12;
  u16* dst = aout + ((size_t)b * 2304 + q0 + wq * 32 + l31) * 768 + head * 64 + h * 32;
  #pragma unroll
  for (int j = 0; j < 4; ++j)
    *(short8*)(dst + j * 8) = *(const short8*)&Olds[wq][l31][h * 32 + j * 8];
}

// ------------------------------------------------------------------
extern "C" void kernel_launch(void* const* d_in, const int* in_sizes, int n_in,
                              void* d_out, int out_size, void* d_ws, size_t ws_size,
                              hipStream_t stream)
{
  (void)in_sizes; (void)n_in; (void)out_size; (void)ws_size;
  const float* x     = (const float*)d_in[0];
  const float* qkvw  = (const float*)d_in[1];
  const float* qkvb  = (const float*)d_in[2];
  const float* projw = (const float*)d_in[3];
  const float* projb = (const float*)d_in[4];
  const float* rph   = (const float*)d_in[5];
  const float* rpw   = (const float*)d_in[6];
  float* out = (float*)d_out;

  char* p = (char*)d_ws;
  u16* wqkv  = (u16*)p;  p += (size_t)2304 * 768 * 2;
  u16* wproj = (u16*)p;  p += (size_t)768 * 768 * 2;
  u16* rphb  = (u16*)p;  p += (size_t)95 * 64 * 2;
  u16* rpwb  = (u16*)p;  p += (size_t)95 * 64 * 2;
  u16* qb    = (u16*)p;  p += (size_t)24 * 2304 * 64 * 2;
  u16* kb    = (u16*)p;  p += (size_t)24 * 2304 * 64 * 2;
  u16* vb    = (u16*)p;  p += (size_t)24 * 2304 * 64 * 2;
  u16* vT    = (u16*)p;  p += (size_t)24 * 64 * 2304 * 2;
  u16* aout  = (u16*)p;  p += (size_t)4608 * 768 * 2;

  cast_kernel<<<dim3(2304 * 768 / 4 / 256), dim3(256), 0, stream>>>(qkvw, wqkv, 2304 * 768);
  cast_kernel<<<dim3(768 * 768 / 4 / 256), dim3(256), 0, stream>>>(projw, wproj, 768 * 768);
  cast_kernel<<<dim3(6), dim3(256), 0, stream>>>(rph, rphb, 95 * 64);
  cast_kernel<<<dim3(6), dim3(256), 0, stream>>>(rpw, rpwb, 95 * 64);
  gemm_k768<true, true><<<dim3(36, 18), dim3(256), 0, stream>>>(x, wqkv, qkvb, qb, kb, vb);
  vtrans<<<dim3(36, 24), dim3(256), 0, stream>>>(vb, vT);
  attn_fused32<<<dim3(576), dim3(384), 0, stream>>>(qb, kb, vT, rphb, rpwb, aout);
  gemm_k768<false, false><<<dim3(36, 6), dim3(256), 0, stream>>>(aout, wproj, projb, out, nullptr, nullptr);
}

// Round 5
// 171.814 us; speedup vs baseline: 1.4189x; 1.4189x over previous
//
#include <hip/hip_runtime.h>

typedef unsigned short u16;
typedef unsigned int u32;
typedef __attribute__((ext_vector_type(8))) short short8;   // 8 bf16 = MFMA A/B frag
typedef __attribute__((ext_vector_type(4))) float f32x4;
typedef __attribute__((ext_vector_type(16))) float f32x16;
typedef __attribute__((ext_vector_type(2))) unsigned int u32x2;

__device__ __forceinline__ float bf2f(u16 u){
  union { u32 i; float f; } x; x.i = ((u32)u) << 16; return x.f;
}
__device__ __forceinline__ u16 f2bf(float f){
  union { float f; u32 i; } x; x.f = f;
  u32 r = x.i + 0x7fffu + ((x.i >> 16) & 1u);   // RNE
  return (u16)(r >> 16);
}
__device__ __forceinline__ u32 pack2(float a, float b){
  return (u32)f2bf(a) | ((u32)f2bf(b) << 16);
}
__device__ __forceinline__ u32 cvtpk(float a, float b){
  u32 r; asm("v_cvt_pk_bf16_f32 %0, %1, %2" : "=v"(r) : "v"(a), "v"(b)); return r;
}
__device__ __forceinline__ float bf_lo(u32 w){
  union { u32 i; float f; } x; x.i = w << 16; return x.f;
}
__device__ __forceinline__ float bf_hi(u32 w){
  union { u32 i; float f; } x; x.i = w & 0xffff0000u; return x.f;
}
__device__ __forceinline__ f32x16 mfma32(short8 a, short8 b, f32x16 c){
  return __builtin_amdgcn_mfma_f32_32x32x16_bf16(a, b, c, 0, 0, 0);
}
__device__ __forceinline__ f32x4 mfma16(short8 a, short8 b, f32x4 c){
  return __builtin_amdgcn_mfma_f32_16x16x32_bf16(a, b, c, 0, 0, 0);
}

// ------------------------------------------------------------------
__global__ void cast_kernel(const float* __restrict__ src, u16* __restrict__ dst, int n){
  int i = (blockIdx.x * blockDim.x + threadIdx.x) * 4;
  if (i >= n) return;
  f32x4 v = *(const f32x4*)(src + i);
  *(u32*)(dst + i)     = pack2(v[0], v[1]);
  *(u32*)(dst + i + 2) = pack2(v[2], v[3]);
}

// ------------------------------------------------------------------
// 128x128-tile GEMM, K=768. C[m][n] = sum_k A[m][k]*B[n][k] + bias[n]
// ------------------------------------------------------------------
template<bool AF32, bool QKV>
__global__ __launch_bounds__(256) void gemm_k768(
    const void* __restrict__ Ap, const u16* __restrict__ Bp,
    const float* __restrict__ bias,
    void* __restrict__ o0, u16* __restrict__ ok, u16* __restrict__ ov)
{
  __shared__ u16 As[128][40];
  __shared__ u16 Bs[128][40];
  const int bm0 = blockIdx.x * 128, bn0 = blockIdx.y * 128;
  const int tid = threadIdx.x, lane = tid & 63, wave = tid >> 6;
  const int g = lane >> 4, m16 = lane & 15;
  const int wr = wave >> 1, wc = wave & 1;

  f32x4 acc[4][4];
  #pragma unroll
  for (int i = 0; i < 4; ++i)
    #pragma unroll
    for (int j = 0; j < 4; ++j) acc[i][j] = (f32x4){0.f, 0.f, 0.f, 0.f};

  const int br = tid >> 1, bh8 = (tid & 1) * 16;

  for (int k0 = 0; k0 < 768; k0 += 32) {
    __syncthreads();
    if constexpr (AF32) {
      const float* A = (const float*)Ap;
      #pragma unroll
      for (int p = 0; p < 2; ++p) {
        int slot = tid + p * 256;
        int r = slot >> 2, c8 = (slot & 3) * 8;
        const float* src = A + (size_t)(bm0 + r) * 768 + k0 + c8;
        f32x4 a0 = *(const f32x4*)src;
        f32x4 a1 = *(const f32x4*)(src + 4);
        u32* d = (u32*)&As[r][c8];
        d[0] = pack2(a0[0], a0[1]); d[1] = pack2(a0[2], a0[3]);
        d[2] = pack2(a1[0], a1[1]); d[3] = pack2(a1[2], a1[3]);
      }
    } else {
      const u16* A = (const u16*)Ap;
      const u16* src = A + (size_t)(bm0 + br) * 768 + k0 + bh8;
      *(short8*)&As[br][bh8]     = *(const short8*)src;
      *(short8*)&As[br][bh8 + 8] = *(const short8*)(src + 8);
    }
    const u16* bsrc = Bp + (size_t)(bn0 + br) * 768 + k0 + bh8;
    *(short8*)&Bs[br][bh8]     = *(const short8*)bsrc;
    *(short8*)&Bs[br][bh8 + 8] = *(const short8*)(bsrc + 8);
    __syncthreads();

    short8 af[4], bf[4];
    #pragma unroll
    for (int i = 0; i < 4; ++i) {
      af[i] = *(const short8*)&As[wr * 64 + i * 16 + m16][g * 8];
      bf[i] = *(const short8*)&Bs[wc * 64 + i * 16 + m16][g * 8];
    }
    #pragma unroll
    for (int i = 0; i < 4; ++i)
      #pragma unroll
      for (int j = 0; j < 4; ++j)
        acc[i][j] = __builtin_amdgcn_mfma_f32_16x16x32_bf16(af[i], bf[j], acc[i][j], 0, 0, 0);
  }

  #pragma unroll
  for (int i = 0; i < 4; ++i) {
    #pragma unroll
    for (int j = 0; j < 4; ++j) {
      int n = bn0 + wc * 64 + j * 16 + m16;
      float bs = bias[n];
      #pragma unroll
      for (int r = 0; r < 4; ++r) {
        int m = bm0 + wr * 64 + i * 16 + g * 4 + r;
        float v = acc[i][j][r] + bs;
        if constexpr (QKV) {
          int b = m / 2304, t = m - b * 2304;
          int which = n / 768, rem = n - which * 768;
          int hh = rem >> 6, d = rem & 63;
          u16* dst = which == 0 ? (u16*)o0 : (which == 1 ? ok : ov);
          dst[(size_t)((b * 12 + hh) * 2304 + t) * 64 + d] = f2bf(v);
        } else {
          ((float*)o0)[(size_t)m * 768 + n] = v;
        }
      }
    }
  }
}

// ------------------------------------------------------------------
// v [bh][2304][64] -> vT [bh][64][2304]
// ------------------------------------------------------------------
__global__ __launch_bounds__(256) void vtrans(const u16* __restrict__ v, u16* __restrict__ vT){
  const int bh = blockIdx.y, t0 = blockIdx.x * 64;
  __shared__ u16 Tl[64][66];
  const int tid = threadIdx.x;
  #pragma unroll
  for (int p = 0; p < 2; ++p) {
    int slot = tid + p * 256;
    int r = slot >> 3, c0 = (slot & 7) * 8;
    short8 val = *(const short8*)(v + (size_t)(bh * 2304 + t0 + r) * 64 + c0);
    #pragma unroll
    for (int j = 0; j < 8; ++j) Tl[c0 + j][r] = (u16)val[j];
  }
  __syncthreads();
  #pragma unroll
  for (int p = 0; p < 2; ++p) {
    int slot = tid + p * 256;
    int d = slot >> 3, c0 = (slot & 7) * 8;
    short8 o;
    #pragma unroll
    for (int j = 0; j < 8; ++j) o[j] = (short)Tl[d][c0 + j];
    *(short8*)(vT + ((size_t)bh * 64 + d) * 2304 + t0 + c0) = o;
  }
}

// ------------------------------------------------------------------
// Fused attention, 32x32x16 MFMA. Block = 128 q-rows x one bh; 4 waves,
// each owns 32 q-rows; all share LDS-staged K/V tiles (coalesced loads,
// XOR-swizzled rows vs 128B bank period). Async staging: issue loads for
// tile i+1 -> compute tile i -> ds_write -> ONE barrier per tile.
// Swapped QK^T: lane-local softmax; defer-max; PV via lane^32 exchange.
// ------------------------------------------------------------------
#define LOG2E 1.4426950408889634f
#define SSC   0.18033688011f      /* 0.125 * LOG2E */

__global__ __launch_bounds__(256, 2) void attn_fused32(
    const u16* __restrict__ qbuf, const u16* __restrict__ kbuf, const u16* __restrict__ vTbuf,
    const u16* __restrict__ rphb, const u16* __restrict__ rpwb, u16* __restrict__ aout)
{
  // XCD-chunked swizzle: 432 = 8 * 54; 54 consecutive blocks per XCD = 3 full bh
  int flat = blockIdx.x;
  flat = (flat & 7) * 54 + (flat >> 3);
  const int bh = flat / 18, qblk = flat - bh * 18;
  const int q0 = qblk * 128;

  const int tid = threadIdx.x, wave = tid >> 6, lane = tid & 63;
  const int l31 = lane & 31, h = lane >> 5;
  const int m16 = lane & 15, g = lane >> 4;
  const int rsub = lane >> 3, slot = lane & 7;   // staging lane split

  __shared__ u16 KV[2][2][4096];    // [buf][K|V][row*64 + swizzled-slot]
  __shared__ u16 RelH[128][52];     // bf16, pre-scaled by LOG2E (wave-private rows)
  __shared__ u16 RelW[128][52];
  __shared__ u16 Olds[4][32][72];   // epilogue transpose buffer

  const size_t bhq = (size_t)bh * 2304;
  const u16* kbase = kbuf + bhq * 64;
  const u16* vbase = vTbuf + (size_t)bh * 64 * 2304;

  // ---- issue stage of tile 0 (coalesced: lane = 8 rows x 8 slots = 1KB/instr) ----
  short8 kreg[2], vreg[2];
  #pragma unroll
  for (int q = 0; q < 2; ++q) {
    const int row = wave * 16 + q * 8 + rsub;
    kreg[q] = *(const short8*)(kbase + (size_t)row * 64 + slot * 8);
    vreg[q] = *(const short8*)(vbase + (size_t)row * 2304 + slot * 8);
  }

  // ---- prologue: rel-pos tables via MFMA (wave-private rows, no barrier) ----
  #pragma unroll
  for (int half = 0; half < 2; ++half) {
    const int it = wave * 2 + half;
    const u16* qap = qbuf + (bhq + q0 + it * 16 + m16) * 64;
    short8 qa0 = *(const short8*)(qap + g * 8);
    short8 qa1 = *(const short8*)(qap + 32 + g * 8);
    #pragma unroll
    for (int tb = 0; tb < 2; ++tb) {
      const u16* rt = tb ? rpwb : rphb;
      u16* tbl = tb ? &RelW[0][0] : &RelH[0][0];
      for (int jt = 0; jt < 6; ++jt) {
        f32x4 c = {0.f, 0.f, 0.f, 0.f};
        const u16* bp = rt + (jt * 16 + m16) * 64;
        short8 b0 = *(const short8*)(bp + g * 8);
        short8 b1 = *(const short8*)(bp + 32 + g * 8);
        c = mfma16(qa0, b0, c);
        c = mfma16(qa1, b1, c);
        const int j = jt * 16 + m16;
        #pragma unroll
        for (int r = 0; r < 4; ++r) {
          const int ql = it * 16 + g * 4 + r;
          const int gq = q0 + ql;
          const int qh = gq / 48;
          const int base = tb ? (gq - qh * 48) : qh;
          const int kidx = base - j + 47;
          if (kidx >= 0 && kidx < 48) tbl[ql * 52 + kidx] = f2bf(c[r] * LOG2E);
        }
      }
    }
  }

  // ---- write stage 0 (swizzled) ----
  #pragma unroll
  for (int q = 0; q < 2; ++q) {
    const int row = wave * 16 + q * 8 + rsub;
    const int ss = (slot ^ (row & 7)) * 8;
    *(short8*)&KV[0][0][row * 64 + ss] = kreg[q];
    *(short8*)&KV[0][1][row * 64 + ss] = vreg[q];
  }
  __syncthreads();

  // ---- persistent Q B-frags ----
  const int qloc = wave * 32 + l31;
  const u16* qrp = qbuf + (bhq + q0 + qloc) * 64;
  short8 qf0 = *(const short8*)(qrp + h * 8);
  short8 qf1 = *(const short8*)(qrp + 16 + h * 8);
  short8 qf2 = *(const short8*)(qrp + 32 + h * 8);
  short8 qf3 = *(const short8*)(qrp + 48 + h * 8);

  f32x16 oA, oB;
  #pragma unroll
  for (int i = 0; i < 16; ++i) { oA[i] = 0.f; oB[i] = 0.f; }
  float mrun = -1e30f;
  float lr0 = 0.f, lr1 = 0.f, lr2 = 0.f, lr3 = 0.f;

  const int sw = l31 & 7;           // fragment-read swizzle key
  int cur = 0;

  for (int kt = 0; kt < 36; ++kt) {
    const int k0 = kt * 64;
    const int kh0 = (kt * 4) / 3;            // k0 / 48
    const int rem0 = k0 - kh0 * 48;          // in {0,16,32}

    // ---- issue next tile's coalesced loads (latency hides under compute) ----
    if (kt < 35) {
      const int kn = k0 + 64;
      #pragma unroll
      for (int q = 0; q < 2; ++q) {
        const int row = wave * 16 + q * 8 + rsub;
        kreg[q] = *(const short8*)(kbase + (size_t)(kn + row) * 64 + slot * 8);
        vreg[q] = *(const short8*)(vbase + (size_t)row * 2304 + kn + slot * 8);
      }
    }

    const u16* Kb = &KV[cur][0][0];
    const u16* Vb = &KV[cur][1][0];

    // ---- bias reads (LDS, independent) ----
    float rh0 = bf2f(RelH[qloc][kh0]);
    float rh1 = bf2f(RelH[qloc][kh0 + 1]);
    u32x2 rw[8];
    float rhg[8];
    #pragma unroll
    for (int ta = 0; ta < 8; ++ta) {
      const int s0 = rem0 + (ta >> 2) * 32 + (ta & 3) * 8 + h * 4;
      const int kwb = s0 >= 48 ? s0 - 48 : s0;
      rhg[ta] = s0 >= 48 ? rh1 : rh0;
      rw[ta] = *(const u32x2*)&RelW[qloc][kwb];
    }

    // ---- QK^T: S^T[64k][32q] from LDS fragments ----
    f32x16 st0, st1;
    #pragma unroll
    for (int i = 0; i < 16; ++i) { st0[i] = 0.f; st1[i] = 0.f; }
    #pragma unroll
    for (int dc = 0; dc < 4; ++dc) {
      const int ch = dc * 2 + h;
      short8 ka0 = *(const short8*)(Kb + l31 * 64 + ((ch ^ sw) * 8));
      short8 ka1 = *(const short8*)(Kb + (32 + l31) * 64 + ((ch ^ sw) * 8));
      short8 qfc = dc == 0 ? qf0 : dc == 1 ? qf1 : dc == 2 ? qf2 : qf3;
      st0 = mfma32(ka0, qfc, st0);
      st1 = mfma32(ka1, qfc, st1);
    }

    // ---- logits + per-lane tmax ----
    float tmax = -1e30f;
    #pragma unroll
    for (int t = 0; t < 2; ++t) {
      f32x16& stt = t ? st1 : st0;
      #pragma unroll
      for (int a = 0; a < 4; ++a) {
        const int ta = t * 4 + a;
        const float b0 = rhg[ta] + bf_lo(rw[ta].x);
        const float b1 = rhg[ta] + bf_hi(rw[ta].x);
        const float b2 = rhg[ta] + bf_lo(rw[ta].y);
        const float b3 = rhg[ta] + bf_hi(rw[ta].y);
        stt[a * 4 + 0] = fmaf(stt[a * 4 + 0], SSC, b0);
        stt[a * 4 + 1] = fmaf(stt[a * 4 + 1], SSC, b1);
        stt[a * 4 + 2] = fmaf(stt[a * 4 + 2], SSC, b2);
        stt[a * 4 + 3] = fmaf(stt[a * 4 + 3], SSC, b3);
        tmax = fmaxf(tmax, fmaxf(fmaxf(stt[a * 4 + 0], stt[a * 4 + 1]),
                                 fmaxf(stt[a * 4 + 2], stt[a * 4 + 3])));
      }
    }

    // ---- defer-max online softmax (log2 domain) ----
    if (__any(tmax > mrun + 8.f)) {
      float tm = fmaxf(tmax, __shfl_xor(tmax, 32));
      float mnew = fmaxf(mrun, tm);
      float al = exp2f(mrun - mnew);
      #pragma unroll
      for (int i = 0; i < 16; ++i) { oA[i] *= al; oB[i] *= al; }
      lr0 *= al; lr1 *= al; lr2 *= al; lr3 *= al;
      mrun = mnew;
    }
    #pragma unroll
    for (int i = 0; i < 16; ++i) {
      st0[i] = exp2f(st0[i] - mrun);
      st1[i] = exp2f(st1[i] - mrun);
    }
    #pragma unroll
    for (int i = 0; i < 4; ++i) {
      lr0 += st0[4 * i + 0] + st1[4 * i + 0];
      lr1 += st0[4 * i + 1] + st1[4 * i + 1];
      lr2 += st0[4 * i + 2] + st1[4 * i + 2];
      lr3 += st0[4 * i + 3] + st1[4 * i + 3];
    }

    // ---- pack P -> bf16, lane^32 exchange, PV from LDS V-frags ----
    #pragma unroll
    for (int j = 0; j < 4; ++j) {
      f32x16& stt = (j >> 1) ? st1 : st0;
      const int a0 = (j & 1) * 2;
      u32 A00 = cvtpk(stt[a0 * 4 + 0], stt[a0 * 4 + 1]);
      u32 A01 = cvtpk(stt[a0 * 4 + 2], stt[a0 * 4 + 3]);
      u32 A10 = cvtpk(stt[a0 * 4 + 4], stt[a0 * 4 + 5]);
      u32 A11 = cvtpk(stt[a0 * 4 + 6], stt[a0 * 4 + 7]);
      u32 sx0 = __shfl_xor(A00, 32), sx1 = __shfl_xor(A01, 32);
      u32 sy0 = __shfl_xor(A10, 32), sy1 = __shfl_xor(A11, 32);
      short8 pb;
      u32* pw = (u32*)&pb;
      pw[0] = h ? sy0 : A00;
      pw[1] = h ? sy1 : A01;
      pw[2] = h ? A10 : sx0;
      pw[3] = h ? A11 : sx1;
      const int ch = j * 2 + h;
      short8 va  = *(const short8*)(Vb + l31 * 64 + ((ch ^ sw) * 8));
      short8 vb_ = *(const short8*)(Vb + (32 + l31) * 64 + ((ch ^ sw) * 8));
      oA = mfma32(va, pb, oA);
      oB = mfma32(vb_, pb, oB);
    }

    // ---- publish next tile (swizzled write), one barrier ----
    if (kt < 35) {
      #pragma unroll
      for (int q = 0; q < 2; ++q) {
        const int row = wave * 16 + q * 8 + rsub;
        const int ss = (slot ^ (row & 7)) * 8;
        *(short8*)&KV[cur ^ 1][0][row * 64 + ss] = kreg[q];
        *(short8*)&KV[cur ^ 1][1][row * 64 + ss] = vreg[q];
      }
    }
    __syncthreads();
    cur ^= 1;
  }

  // ---- epilogue: normalize, transpose via per-wave LDS, coalesced store ----
  float lrt = lr0 + lr1 + lr2 + lr3;
  lrt += __shfl_xor(lrt, 32);
  const float inv = 1.0f / lrt;
  #pragma unroll
  for (int dt = 0; dt < 2; ++dt) {
    const f32x16& oo = dt ? oB : oA;
    #pragma unroll
    for (int rp = 0; rp < 8; ++rp) {
      u32 w = cvtpk(oo[2 * rp] * inv, oo[2 * rp + 1] * inv);
      const int d = 32 * dt + 2 * (rp & 1) + 8 * (rp >> 1) + 4 * h;
      *(u32*)&Olds[wave][l31][d] = w;
    }
  }
  asm volatile("s_waitcnt lgkmcnt(0)" ::: "memory");
  const int b = bh / 12, head = bh - b * 12;
  const int tok = q0 + wave * 32 + l31;
  u16* dst = aout + ((size_t)b * 2304 + tok) * 768 + head * 64 + h * 32;
  #pragma unroll
  for (int j = 0; j < 4; ++j)
    *(short8*)(dst + j * 8) = *(const short8*)&Olds[wave][l31][h * 32 + j * 8];
}

// ------------------------------------------------------------------
extern "C" void kernel_launch(void* const* d_in, const int* in_sizes, int n_in,
                              void* d_out, int out_size, void* d_ws, size_t ws_size,
                              hipStream_t stream)
{
  (void)in_sizes; (void)n_in; (void)out_size; (void)ws_size;
  const float* x     = (const float*)d_in[0];
  const float* qkvw  = (const float*)d_in[1];
  const float* qkvb  = (const float*)d_in[2];
  const float* projw = (const float*)d_in[3];
  const float* projb = (const float*)d_in[4];
  const float* rph   = (const float*)d_in[5];
  const float* rpw   = (const float*)d_in[6];
  float* out = (float*)d_out;

  char* p = (char*)d_ws;
  u16* wqkv  = (u16*)p;  p += (size_t)2304 * 768 * 2;
  u16* wproj = (u16*)p;  p += (size_t)768 * 768 * 2;
  u16* rphb  = (u16*)p;  p += (size_t)96 * 64 * 2;
  u16* rpwb  = (u16*)p;  p += (size_t)96 * 64 * 2;
  u16* qb    = (u16*)p;  p += (size_t)24 * 2304 * 64 * 2;
  u16* kb    = (u16*)p;  p += (size_t)24 * 2304 * 64 * 2;
  u16* vb    = (u16*)p;  p += (size_t)24 * 2304 * 64 * 2;
  u16* vT    = (u16*)p;  p += (size_t)24 * 64 * 2304 * 2;
  u16* aout  = (u16*)p;  p += (size_t)4608 * 768 * 2;

  cast_kernel<<<dim3(2304 * 768 / 4 / 256), dim3(256), 0, stream>>>(qkvw, wqkv, 2304 * 768);
  cast_kernel<<<dim3(768 * 768 / 4 / 256), dim3(256), 0, stream>>>(projw, wproj, 768 * 768);
  cast_kernel<<<dim3(6), dim3(256), 0, stream>>>(rph, rphb, 95 * 64);
  cast_kernel<<<dim3(6), dim3(256), 0, stream>>>(rpw, rpwb, 95 * 64);
  gemm_k768<true, true><<<dim3(36, 18), dim3(256), 0, stream>>>(x, wqkv, qkvb, qb, kb, vb);
  vtrans<<<dim3(36, 24), dim3(256), 0, stream>>>(vb, vT);
  attn_fused32<<<dim3(432), dim3(256), 0, stream>>>(qb, kb, vT, rphb, rpwb, aout);
  gemm_k768<false, false><<<dim3(36, 6), dim3(256), 0, stream>>>(aout, wproj, projb, out, nullptr, nullptr);
}